// Round 17
// baseline (136.253 us; speedup 1.0000x reference)
//
#include <hip/hip_runtime.h>

#define D_IN 256
#define D_OUT 128
#define ALPHA 0.2f
#define RB 64           // src nodes per bucket
#define RBSH 6
#define NBMAX 1600
#define CH 8192         // edges per bfill-role block
#define CAPG 1536       // fixed per-bucket key capacity (mean 1024, +16 sigma)
#define OVFCAP 32768
#define BM 64           // gemm-role rows per block

typedef __attribute__((ext_vector_type(8))) short bf16x8;
typedef __attribute__((ext_vector_type(4))) float f32x4;

__device__ inline unsigned short f2bf(float f) {
    unsigned int u = __float_as_uint(f);
    return (unsigned short)((u + 0x7FFFu + ((u >> 16) & 1u)) >> 16);
}
__device__ inline float bf2f(unsigned short u) {
    return __uint_as_float(((unsigned int)u) << 16);
}
// gfx950 native packed fp32->bf16 (RNE); no builtin exposed -> inline asm.
__device__ inline unsigned int cvt_pk_bf16(float lo, float hi) {
    unsigned int r;
    asm("v_cvt_pk_bf16_f32 %0, %1, %2" : "=v"(r) : "v"(lo), "v"(hi));
    return r;
}

// ---------------- W -> WTb (transposed bf16) ----------------
__global__ __launch_bounds__(256) void k_wt(const float* __restrict__ W,
                                            unsigned short* __restrict__ WTb) {
    const int ncol = blockIdx.x;
    const int k = threadIdx.x;
    WTb[(size_t)ncol * 256 + k] = f2bf(W[(size_t)k * 128 + ncol]);
}

// ===== fused heterogeneous kernel: blocks [0,nbf) = bfill, [nbf,..) = GEMM =====
// GEMM role: BM=64, FULL K=256 staged once (32KB LDS), one barrier pair.
__global__ __launch_bounds__(256) void k_fused(const float* __restrict__ x,
                                               const unsigned short* __restrict__ WTb,
                                               const float* __restrict__ a,
                                               unsigned short* __restrict__ hb,
                                               float* __restrict__ f_src,
                                               float* __restrict__ f_dst, int n,
                                               const int* __restrict__ src,
                                               const int* __restrict__ dst,
                                               int* __restrict__ gcnt,
                                               int2* __restrict__ ovf,
                                               int* __restrict__ gkeys, int E, int nb,
                                               int nbf) {
    __shared__ char smem[BM * D_IN * 2];       // 32 KB union (bfill cnt/bas | x tile)
    __shared__ float sFp[BM][2][2];            // gemm epilogue buffer, 1 KB
    const int t = threadIdx.x;

    if (blockIdx.x < nbf) {
        // ---------------- bfill role ----------------
        int* cnt = (int*)smem;                 // [NBMAX]
        int* bas = cnt + NBMAX;                // [NBMAX]  (12.8 KB < 32 KB)
        const int e0 = blockIdx.x * CH;
        const int e1 = min(e0 + CH, E);
        for (int i = t; i < nb; i += 256) cnt[i] = 0;
        __syncthreads();
        for (int e = e0 + t; e < e1; e += 256) atomicAdd(&cnt[src[e] >> RBSH], 1);
        __syncthreads();
        for (int b = t; b < nb; b += 256) {
            int c = cnt[b];
            bas[b] = c ? atomicAdd(&gcnt[b], c) : 0;
            cnt[b] = 0;
        }
        __syncthreads();
        for (int e = e0 + t; e < e1; e += 256) {
            int s = src[e], d = dst[e];
            int b = s >> RBSH;
            int key = ((s & (RB - 1)) << 17) | d;
            int r = bas[b] + atomicAdd(&cnt[b], 1);
            if (r < CAPG) {
                gkeys[b * CAPG + r] = key;
            } else {
                int o = atomicAdd(&gcnt[nb], 1);
                if (o < OVFCAP) ovf[o] = make_int2(b, key);
            }
        }
        return;
    }

    // ---------------- GEMM role (BM=64, full-K LDS, swizzled) ----------------
    unsigned short* sA = (unsigned short*)smem;    // [64][256] bf16, swizzled granules
    const int l = t & 63;
    const int w = t >> 6;
    const int wr = w >> 1, wc = w & 1;
    const int row0 = (blockIdx.x - nbf) * BM;
    const int col0 = wc * 64;
    const int lr = l & 15;
    const int g = l >> 4;
    const int lk8 = g * 8;

    f32x4 acc[2][4] = {};
    const unsigned short* bp[4];
    #pragma unroll
    for (int ni = 0; ni < 4; ++ni)
        bp[ni] = WTb + (size_t)(col0 + ni * 16 + lr) * 256 + lk8;

    // ---- stage full x tile: fp32 -> bf16 LDS, one phase, 8 iters in flight ----
    {
        const int rr = t >> 5;          // 0..7
        const int cc = (t & 31) * 8;    // 0..248
        const int gw = cc >> 3;         // granule 0..31
        #pragma unroll
        for (int it = 0; it < 8; ++it) {
            int r = it * 8 + rr;
            int gr = row0 + r;
            float4 fa, fb;
            if (gr < n) {
                const float* xp = &x[(size_t)gr * D_IN + cc];
                fa = *(const float4*)xp;
                fb = *(const float4*)(xp + 4);
            } else {
                fa = make_float4(0.f, 0.f, 0.f, 0.f);
                fb = fa;
            }
            uint4 v;
            v.x = cvt_pk_bf16(fa.x, fa.y);
            v.y = cvt_pk_bf16(fa.z, fa.w);
            v.z = cvt_pk_bf16(fb.x, fb.y);
            v.w = cvt_pk_bf16(fb.z, fb.w);
            int js = gw ^ ((r & 15) << 1);     // swizzled 16B granule (32/row)
            *(uint4*)&sA[r * D_IN + js * 8] = v;
        }
    }
    __syncthreads();

    #pragma unroll
    for (int k0 = 0; k0 < D_IN; k0 += 32) {
        bf16x8 af[2], bfr[4];
        #pragma unroll
        for (int mi = 0; mi < 2; ++mi) {
            int row_l = wr * 32 + mi * 16 + lr;
            int js = ((k0 >> 3) + g) ^ ((row_l & 15) << 1);
            af[mi] = *(const bf16x8*)&sA[row_l * D_IN + js * 8];
        }
        #pragma unroll
        for (int ni = 0; ni < 4; ++ni)
            bfr[ni] = *(const bf16x8*)(bp[ni] + k0);
        #pragma unroll
        for (int mi = 0; mi < 2; ++mi)
            #pragma unroll
            for (int ni = 0; ni < 4; ++ni)
                acc[mi][ni] = __builtin_amdgcn_mfma_f32_16x16x32_bf16(
                    af[mi], bfr[ni], acc[mi][ni], 0, 0, 0);
    }

    // ---- hb store (C/D: col = lane&15, row = g*4 + q), cvt_pk pairs ----
    #pragma unroll
    for (int mi = 0; mi < 2; ++mi) {
        #pragma unroll
        for (int q = 0; q < 4; ++q) {
            int r = row0 + wr * 32 + mi * 16 + g * 4 + q;
            if (r < n) {
                unsigned int a01 = cvt_pk_bf16(acc[mi][0][q], acc[mi][1][q]);
                unsigned int a23 = cvt_pk_bf16(acc[mi][2][q], acc[mi][3][q]);
                unsigned short* hp = &hb[(size_t)r * D_OUT + col0 + lr];
                hp[0]  = (unsigned short)(a01 & 0xFFFF);
                hp[16] = (unsigned short)(a01 >> 16);
                hp[32] = (unsigned short)(a23 & 0xFFFF);
                hp[48] = (unsigned short)(a23 >> 16);
            }
        }
    }

    // ---- fused f_src/f_dst from fp32 acc ----
    float asv[4], adv[4];
    #pragma unroll
    for (int ni = 0; ni < 4; ++ni) {
        asv[ni] = a[col0 + ni * 16 + lr];
        adv[ni] = a[D_OUT + col0 + ni * 16 + lr];
    }
    #pragma unroll
    for (int mi = 0; mi < 2; ++mi) {
        #pragma unroll
        for (int q = 0; q < 4; ++q) {
            float fs = 0.f, fd = 0.f;
            #pragma unroll
            for (int ni = 0; ni < 4; ++ni) {
                float v = acc[mi][ni][q];
                fs = fmaf(v, asv[ni], fs);
                fd = fmaf(v, adv[ni], fd);
            }
            #pragma unroll
            for (int m = 1; m < 16; m <<= 1) {
                fs += __shfl_xor(fs, m);
                fd += __shfl_xor(fd, m);
            }
            if (lr == 0) {
                int rl = wr * 32 + mi * 16 + g * 4 + q;
                sFp[rl][wc][0] = fs;
                sFp[rl][wc][1] = fd;
            }
        }
    }
    __syncthreads();
    if (t < BM) {
        int r = row0 + t;
        if (r < n) {
            f_src[r] = sFp[t][0][0] + sFp[t][1][0];
            f_dst[r] = sFp[t][0][1] + sFp[t][1][1];
        }
    }
}

// -------- aggregation: block/bucket, LDS lists, 2-edge 32-lane pass 3 --------
__global__ __launch_bounds__(512, 8) void k_bagg(const unsigned short* __restrict__ hb,
                                                 const float* __restrict__ f_src,
                                                 const float* __restrict__ f_dst,
                                                 const int* __restrict__ gcnt,
                                                 const int2* __restrict__ ovf,
                                                 const int* __restrict__ gkeys,
                                                 float* __restrict__ out, int n, int nb) {
    __shared__ int2 sdw[CAPG];       // (dst, weight-bits), grouped by local src
    __shared__ int nbase[RB];
    __shared__ int ncnt[RB];
    __shared__ int ncur[RB];
    __shared__ float fsl[RB];
    __shared__ int sc[RB];
    const int t = threadIdx.x;
    const int b = blockIdx.x;
    const int s0 = b * RB;
    const int nn = min(RB, n - s0);
    const int beg = b * CAPG;
    const int stored = min(gcnt[b], CAPG);
    const int ovf_n = min(gcnt[nb], OVFCAP);

    for (int i = t; i < RB; i += 512) {
        ncnt[i] = 0;
        fsl[i] = (i < nn) ? f_src[s0 + i] : 0.f;
    }
    __syncthreads();

    for (int i = t; i < stored; i += 512)
        atomicAdd(&ncnt[gkeys[beg + i] >> 17], 1);
    __syncthreads();

    if (t < RB) sc[t] = ncnt[t];
    __syncthreads();
    for (int off = 1; off < RB; off <<= 1) {
        int v = 0;
        if (t < RB && t >= off) v = sc[t - off];
        __syncthreads();
        if (t < RB) sc[t] += v;
        __syncthreads();
    }
    if (t < RB) {
        nbase[t] = sc[t] - ncnt[t];
        ncur[t]  = sc[t] - ncnt[t];
    }
    __syncthreads();

    for (int i = t; i < stored; i += 512) {
        int k = gkeys[beg + i];
        int d = k & 0x1FFFF, ls = k >> 17;
        float tmp = fsl[ls] + f_dst[d];
        float w = __expf(-((tmp > 0.f) ? tmp : ALPHA * tmp));
        int pos = atomicAdd(&ncur[ls], 1);
        sdw[pos] = make_int2(d, __float_as_int(w));
    }
    __syncthreads();

    const int lane = t & 63, wid = t >> 6;
    const int cl = (lane & 31) * 4;
    const bool isB = lane >= 32;
    for (int ni = wid; ni < nn; ni += 8) {
        const int jb = nbase[ni];
        const int cn = ncnt[ni];
        const int halfA = (cn + 1) >> 1;
        const int halfB = cn - halfA;
        const int lim = isB ? halfB : halfA;
        const int jbh = jb + (isB ? halfA : 0);
        float a0 = 0.f, a1 = 0.f, a2 = 0.f, a3 = 0.f, rowsum = 0.f;
        #pragma unroll 4
        for (int it = 0; it < halfA; ++it) {
            bool valid = it < lim;
            int2 dw = sdw[valid ? (jbh + it) : jb];
            float w = valid ? __int_as_float(dw.y) : 0.f;
            ushort4 hv = *(const ushort4*)&hb[(size_t)dw.x * D_OUT + cl];
            rowsum += w;
            a0 = fmaf(w, bf2f(hv.x), a0);
            a1 = fmaf(w, bf2f(hv.y), a1);
            a2 = fmaf(w, bf2f(hv.z), a2);
            a3 = fmaf(w, bf2f(hv.w), a3);
        }
        if (ovf_n > 0) {
            for (int o = 0; o < ovf_n; ++o) {
                int2 ov = ovf[o];
                if (ov.x == b && (ov.y >> 17) == ni && !isB) {
                    int d = ov.y & 0x1FFFF;
                    float tmp = fsl[ni] + f_dst[d];
                    float w = __expf(-((tmp > 0.f) ? tmp : ALPHA * tmp));
                    ushort4 hv = *(const ushort4*)&hb[(size_t)d * D_OUT + cl];
                    rowsum += w;
                    a0 = fmaf(w, bf2f(hv.x), a0);
                    a1 = fmaf(w, bf2f(hv.y), a1);
                    a2 = fmaf(w, bf2f(hv.z), a2);
                    a3 = fmaf(w, bf2f(hv.w), a3);
                }
            }
        }
        rowsum += __shfl_xor(rowsum, 32);
        a0 += __shfl_xor(a0, 32);
        a1 += __shfl_xor(a1, 32);
        a2 += __shfl_xor(a2, 32);
        a3 += __shfl_xor(a3, 32);
        if (!isB) {
            float inv = 1.f / rowsum;
            a0 *= inv; a1 *= inv; a2 *= inv; a3 *= inv;
            a0 = (a0 > 0.f) ? a0 : (__expf(a0) - 1.f);
            a1 = (a1 > 0.f) ? a1 : (__expf(a1) - 1.f);
            a2 = (a2 > 0.f) ? a2 : (__expf(a2) - 1.f);
            a3 = (a3 > 0.f) ? a3 : (__expf(a3) - 1.f);
            *(float4*)&out[(size_t)(s0 + ni) * D_OUT + cl] =
                make_float4(a0, a1, a2, a3);
        }
    }
}

extern "C" void kernel_launch(void* const* d_in, const int* in_sizes, int n_in,
                              void* d_out, int out_size, void* d_ws, size_t ws_size,
                              hipStream_t stream) {
    const float* x    = (const float*)d_in[0];
    const int*   edge = (const int*)d_in[1];   // JAX no-x64: int64 -> int32
    const float* W    = (const float*)d_in[2];
    const float* a    = (const float*)d_in[3];
    float* out = (float*)d_out;

    const int n = in_sizes[0] / D_IN;
    const int E = in_sizes[1] / 2;
    const int* src = edge;
    const int* dst = edge + E;
    const int nb = (n + RB - 1) / RB;

    char* p = (char*)d_ws;
    unsigned short* hb  = (unsigned short*)p; p += (size_t)n * D_OUT * sizeof(unsigned short);
    unsigned short* WTb = (unsigned short*)p; p += (size_t)D_OUT * D_IN * sizeof(unsigned short);
    float* f_src = (float*)p;  p += (size_t)n * sizeof(float);
    float* f_dst = (float*)p;  p += (size_t)n * sizeof(float);
    int*  gcnt   = (int*)p;    p += (size_t)(nb + 1) * sizeof(int);
    int2* ovf    = (int2*)p;   p += (size_t)OVFCAP * sizeof(int2);
    int*  gkeys  = (int*)p;    p += (size_t)nb * CAPG * sizeof(int);

    const int gemm_blocks = (n + BM - 1) / BM;
    const int nbf = (E + CH - 1) / CH;

    hipMemsetAsync(gcnt, 0, (size_t)(nb + 1) * sizeof(int), stream);
    k_wt<<<D_OUT, 256, 0, stream>>>(W, WTb);
    k_fused<<<nbf + gemm_blocks, 256, 0, stream>>>(x, WTb, a, hb, f_src, f_dst, n,
                                                   src, dst, gcnt, ovf, gkeys, E, nb, nbf);
    k_bagg<<<nb, 512, 0, stream>>>(hb, f_src, f_dst, gcnt, ovf, gkeys, out, n, nb);
}

// Round 18
// 131.339 us; speedup vs baseline: 1.0374x; 1.0374x over previous
//
#include <hip/hip_runtime.h>

#define D_IN 256
#define D_OUT 128
#define ALPHA 0.2f
#define RB 64           // src nodes per bucket
#define RBSH 6
#define NBMAX 1600
#define CH 8192         // edges per bfill-role block
#define CAPG 1536       // fixed per-bucket key capacity (mean 1024, +16 sigma)
#define OVFCAP 32768
#define LKH 128         // K-half staged in LDS (fp32 elems per row)
#define BM 64           // gemm-role rows per block

typedef __attribute__((ext_vector_type(8))) short bf16x8;
typedef __attribute__((ext_vector_type(4))) float f32x4;

__device__ inline unsigned short f2bf(float f) {
    unsigned int u = __float_as_uint(f);
    return (unsigned short)((u + 0x7FFFu + ((u >> 16) & 1u)) >> 16);
}
__device__ inline float bf2f(unsigned short u) {
    return __uint_as_float(((unsigned int)u) << 16);
}
// gfx950 native packed fp32->bf16 (RNE); no builtin exposed -> inline asm.
__device__ inline unsigned int cvt_pk_bf16(float lo, float hi) {
    unsigned int r;
    asm("v_cvt_pk_bf16_f32 %0, %1, %2" : "=v"(r) : "v"(lo), "v"(hi));
    return r;
}
// async global->LDS DMA, 16B per lane; lds dest = wave-uniform base + lane*16
__device__ inline void gload_lds16(const float* g, void* lds) {
    __builtin_amdgcn_global_load_lds(
        (const __attribute__((address_space(1))) void*)(const void*)g,
        (__attribute__((address_space(3))) void*)lds, 16, 0, 0);
}

// ------------- W -> WTb (transposed bf16); block 0 also zeroes gcnt -------------
__global__ __launch_bounds__(256) void k_wt(const float* __restrict__ W,
                                            unsigned short* __restrict__ WTb,
                                            int* __restrict__ gcnt, int nb) {
    if (blockIdx.x == 0) {
        for (int i = threadIdx.x; i <= nb; i += 256) gcnt[i] = 0;
    }
    const int ncol = blockIdx.x;
    const int k = threadIdx.x;
    WTb[(size_t)ncol * 256 + k] = f2bf(W[(size_t)k * 128 + ncol]);
}

// ===== fused heterogeneous kernel: blocks [0,nbf) = bfill, [nbf,..) = GEMM =====
// GEMM role: BM=64, K in 2 halves; fp32 x staged via global_load_lds (async DMA,
// linear LDS dest + pre-swizzled global source); cvt_pk on fragment read.
__global__ __launch_bounds__(256) void k_fused(const float* __restrict__ x,
                                               const unsigned short* __restrict__ WTb,
                                               const float* __restrict__ a,
                                               unsigned short* __restrict__ hb,
                                               float* __restrict__ f_src,
                                               float* __restrict__ f_dst, int n,
                                               const int* __restrict__ src,
                                               const int* __restrict__ dst,
                                               int* __restrict__ gcnt,
                                               int2* __restrict__ ovf,
                                               int* __restrict__ gkeys, int E, int nb,
                                               int nbf) {
    __shared__ char smem[BM * LKH * 4];        // 32 KB union (bfill cnt/bas | fp32 x half)
    __shared__ float sFp[BM][2][2];            // gemm epilogue buffer, 1 KB
    const int t = threadIdx.x;

    if (blockIdx.x < nbf) {
        // ---------------- bfill role ----------------
        int* cnt = (int*)smem;                 // [NBMAX]
        int* bas = cnt + NBMAX;                // [NBMAX]  (12.8 KB < 32 KB)
        const int e0 = blockIdx.x * CH;
        const int e1 = min(e0 + CH, E);
        for (int i = t; i < nb; i += 256) cnt[i] = 0;
        __syncthreads();
        for (int e = e0 + t; e < e1; e += 256) atomicAdd(&cnt[src[e] >> RBSH], 1);
        __syncthreads();
        for (int b = t; b < nb; b += 256) {
            int c = cnt[b];
            bas[b] = c ? atomicAdd(&gcnt[b], c) : 0;
            cnt[b] = 0;
        }
        __syncthreads();
        for (int e = e0 + t; e < e1; e += 256) {
            int s = src[e], d = dst[e];
            int b = s >> RBSH;
            int key = ((s & (RB - 1)) << 17) | d;
            int r = bas[b] + atomicAdd(&cnt[b], 1);
            if (r < CAPG) {
                gkeys[b * CAPG + r] = key;
            } else {
                int o = atomicAdd(&gcnt[nb], 1);
                if (o < OVFCAP) ovf[o] = make_int2(b, key);
            }
        }
        return;
    }

    // ---------------- GEMM role (BM=64, 2 K-halves, async-DMA staged) ----------------
    float* sAf = (float*)smem;                 // [64][128] fp32, swizzled 16B granules
    const int l = t & 63;
    const int w = t >> 6;
    const int wr = w >> 1, wc = w & 1;
    const int row0 = (blockIdx.x - nbf) * BM;
    const int col0 = wc * 64;
    const int lr = l & 15;
    const int g = l >> 4;
    const int lk8 = g * 8;

    f32x4 acc[2][4] = {};
    const unsigned short* bp[4];
    #pragma unroll
    for (int ni = 0; ni < 4; ++ni)
        bp[ni] = WTb + (size_t)(col0 + ni * 16 + lr) * 256 + lk8;

    #pragma unroll
    for (int half = 0; half < 2; ++half) {
        // ---- stage 64 rows x 128 fp32 via global_load_lds (wave w: rows w*16..+15) ----
        {
            const int rh = l >> 5;             // 0 or 1: row within pair
            const int gg = l & 31;             // 16B granule within row
            #pragma unroll
            for (int it = 0; it < 8; ++it) {
                int r = w * 16 + it * 2 + rh;
                int gr = row0 + r;
                if (gr > n - 1) gr = n - 1;    // clamp; stores masked later
                int gs = gg ^ (r & 7);         // pre-swizzled source granule
                const float* gp = x + (size_t)gr * D_IN + half * LKH + gs * 4;
                gload_lds16(gp, (char*)smem + (size_t)(w * 16 + it * 2) * 512);
            }
        }
        __syncthreads();   // drains vmcnt (DMA) for all waves

        #pragma unroll
        for (int k0 = 0; k0 < LKH; k0 += 32) {
            bf16x8 af[2], bfr[4];
            #pragma unroll
            for (int mi = 0; mi < 2; ++mi) {
                int row_l = wr * 32 + mi * 16 + lr;
                int g0 = (k0 >> 2) + g * 2;    // first 16B granule of the 8 fp32
                int gs0 = g0 ^ (row_l & 7);
                int gs1 = (g0 + 1) ^ (row_l & 7);
                float4 f0 = *(const float4*)&sAf[(row_l * 32 + gs0) * 4];
                float4 f1 = *(const float4*)&sAf[(row_l * 32 + gs1) * 4];
                union { uint4 u; bf16x8 v; } cv;
                cv.u.x = cvt_pk_bf16(f0.x, f0.y);
                cv.u.y = cvt_pk_bf16(f0.z, f0.w);
                cv.u.z = cvt_pk_bf16(f1.x, f1.y);
                cv.u.w = cvt_pk_bf16(f1.z, f1.w);
                af[mi] = cv.v;
            }
            #pragma unroll
            for (int ni = 0; ni < 4; ++ni)
                bfr[ni] = *(const bf16x8*)(bp[ni] + half * LKH + k0);
            #pragma unroll
            for (int mi = 0; mi < 2; ++mi)
                #pragma unroll
                for (int ni = 0; ni < 4; ++ni)
                    acc[mi][ni] = __builtin_amdgcn_mfma_f32_16x16x32_bf16(
                        af[mi], bfr[ni], acc[mi][ni], 0, 0, 0);
        }
        __syncthreads();
    }

    // ---- hb store (C/D: col = lane&15, row = g*4 + q), cvt_pk pairs ----
    #pragma unroll
    for (int mi = 0; mi < 2; ++mi) {
        #pragma unroll
        for (int q = 0; q < 4; ++q) {
            int r = row0 + wr * 32 + mi * 16 + g * 4 + q;
            if (r < n) {
                unsigned int a01 = cvt_pk_bf16(acc[mi][0][q], acc[mi][1][q]);
                unsigned int a23 = cvt_pk_bf16(acc[mi][2][q], acc[mi][3][q]);
                unsigned short* hp = &hb[(size_t)r * D_OUT + col0 + lr];
                hp[0]  = (unsigned short)(a01 & 0xFFFF);
                hp[16] = (unsigned short)(a01 >> 16);
                hp[32] = (unsigned short)(a23 & 0xFFFF);
                hp[48] = (unsigned short)(a23 >> 16);
            }
        }
    }

    // ---- fused f_src/f_dst from fp32 acc ----
    float asv[4], adv[4];
    #pragma unroll
    for (int ni = 0; ni < 4; ++ni) {
        asv[ni] = a[col0 + ni * 16 + lr];
        adv[ni] = a[D_OUT + col0 + ni * 16 + lr];
    }
    #pragma unroll
    for (int mi = 0; mi < 2; ++mi) {
        #pragma unroll
        for (int q = 0; q < 4; ++q) {
            float fs = 0.f, fd = 0.f;
            #pragma unroll
            for (int ni = 0; ni < 4; ++ni) {
                float v = acc[mi][ni][q];
                fs = fmaf(v, asv[ni], fs);
                fd = fmaf(v, adv[ni], fd);
            }
            #pragma unroll
            for (int m = 1; m < 16; m <<= 1) {
                fs += __shfl_xor(fs, m);
                fd += __shfl_xor(fd, m);
            }
            if (lr == 0) {
                int rl = wr * 32 + mi * 16 + g * 4 + q;
                sFp[rl][wc][0] = fs;
                sFp[rl][wc][1] = fd;
            }
        }
    }
    __syncthreads();
    if (t < BM) {
        int r = row0 + t;
        if (r < n) {
            f_src[r] = sFp[t][0][0] + sFp[t][1][0];
            f_dst[r] = sFp[t][0][1] + sFp[t][1][1];
        }
    }
}

// -------- aggregation: block/bucket, LDS lists, 2-edge 32-lane pass 3 --------
__global__ __launch_bounds__(512, 8) void k_bagg(const unsigned short* __restrict__ hb,
                                                 const float* __restrict__ f_src,
                                                 const float* __restrict__ f_dst,
                                                 const int* __restrict__ gcnt,
                                                 const int2* __restrict__ ovf,
                                                 const int* __restrict__ gkeys,
                                                 float* __restrict__ out, int n, int nb) {
    __shared__ int2 sdw[CAPG];       // (dst, weight-bits), grouped by local src
    __shared__ int nbase[RB];
    __shared__ int ncnt[RB];
    __shared__ int ncur[RB];
    __shared__ float fsl[RB];
    __shared__ int sc[RB];
    const int t = threadIdx.x;
    const int b = blockIdx.x;
    const int s0 = b * RB;
    const int nn = min(RB, n - s0);
    const int beg = b * CAPG;
    const int stored = min(gcnt[b], CAPG);
    const int ovf_n = min(gcnt[nb], OVFCAP);

    for (int i = t; i < RB; i += 512) {
        ncnt[i] = 0;
        fsl[i] = (i < nn) ? f_src[s0 + i] : 0.f;
    }
    __syncthreads();

    for (int i = t; i < stored; i += 512)
        atomicAdd(&ncnt[gkeys[beg + i] >> 17], 1);
    __syncthreads();

    if (t < RB) sc[t] = ncnt[t];
    __syncthreads();
    for (int off = 1; off < RB; off <<= 1) {
        int v = 0;
        if (t < RB && t >= off) v = sc[t - off];
        __syncthreads();
        if (t < RB) sc[t] += v;
        __syncthreads();
    }
    if (t < RB) {
        nbase[t] = sc[t] - ncnt[t];
        ncur[t]  = sc[t] - ncnt[t];
    }
    __syncthreads();

    for (int i = t; i < stored; i += 512) {
        int k = gkeys[beg + i];
        int d = k & 0x1FFFF, ls = k >> 17;
        float tmp = fsl[ls] + f_dst[d];
        float w = __expf(-((tmp > 0.f) ? tmp : ALPHA * tmp));
        int pos = atomicAdd(&ncur[ls], 1);
        sdw[pos] = make_int2(d, __float_as_int(w));
    }
    __syncthreads();

    const int lane = t & 63, wid = t >> 6;
    const int cl = (lane & 31) * 4;
    const bool isB = lane >= 32;
    for (int ni = wid; ni < nn; ni += 8) {
        const int jb = nbase[ni];
        const int cn = ncnt[ni];
        const int halfA = (cn + 1) >> 1;
        const int halfB = cn - halfA;
        const int lim = isB ? halfB : halfA;
        const int jbh = jb + (isB ? halfA : 0);
        float a0 = 0.f, a1 = 0.f, a2 = 0.f, a3 = 0.f, rowsum = 0.f;
        #pragma unroll 4
        for (int it = 0; it < halfA; ++it) {
            bool valid = it < lim;
            int2 dw = sdw[valid ? (jbh + it) : jb];
            float w = valid ? __int_as_float(dw.y) : 0.f;
            ushort4 hv = *(const ushort4*)&hb[(size_t)dw.x * D_OUT + cl];
            rowsum += w;
            a0 = fmaf(w, bf2f(hv.x), a0);
            a1 = fmaf(w, bf2f(hv.y), a1);
            a2 = fmaf(w, bf2f(hv.z), a2);
            a3 = fmaf(w, bf2f(hv.w), a3);
        }
        if (ovf_n > 0) {
            for (int o = 0; o < ovf_n; ++o) {
                int2 ov = ovf[o];
                if (ov.x == b && (ov.y >> 17) == ni && !isB) {
                    int d = ov.y & 0x1FFFF;
                    float tmp = fsl[ni] + f_dst[d];
                    float w = __expf(-((tmp > 0.f) ? tmp : ALPHA * tmp));
                    ushort4 hv = *(const ushort4*)&hb[(size_t)d * D_OUT + cl];
                    rowsum += w;
                    a0 = fmaf(w, bf2f(hv.x), a0);
                    a1 = fmaf(w, bf2f(hv.y), a1);
                    a2 = fmaf(w, bf2f(hv.z), a2);
                    a3 = fmaf(w, bf2f(hv.w), a3);
                }
            }
        }
        rowsum += __shfl_xor(rowsum, 32);
        a0 += __shfl_xor(a0, 32);
        a1 += __shfl_xor(a1, 32);
        a2 += __shfl_xor(a2, 32);
        a3 += __shfl_xor(a3, 32);
        if (!isB) {
            float inv = 1.f / rowsum;
            a0 *= inv; a1 *= inv; a2 *= inv; a3 *= inv;
            a0 = (a0 > 0.f) ? a0 : (__expf(a0) - 1.f);
            a1 = (a1 > 0.f) ? a1 : (__expf(a1) - 1.f);
            a2 = (a2 > 0.f) ? a2 : (__expf(a2) - 1.f);
            a3 = (a3 > 0.f) ? a3 : (__expf(a3) - 1.f);
            *(float4*)&out[(size_t)(s0 + ni) * D_OUT + cl] =
                make_float4(a0, a1, a2, a3);
        }
    }
}

extern "C" void kernel_launch(void* const* d_in, const int* in_sizes, int n_in,
                              void* d_out, int out_size, void* d_ws, size_t ws_size,
                              hipStream_t stream) {
    const float* x    = (const float*)d_in[0];
    const int*   edge = (const int*)d_in[1];   // JAX no-x64: int64 -> int32
    const float* W    = (const float*)d_in[2];
    const float* a    = (const float*)d_in[3];
    float* out = (float*)d_out;

    const int n = in_sizes[0] / D_IN;
    const int E = in_sizes[1] / 2;
    const int* src = edge;
    const int* dst = edge + E;
    const int nb = (n + RB - 1) / RB;

    char* p = (char*)d_ws;
    unsigned short* hb  = (unsigned short*)p; p += (size_t)n * D_OUT * sizeof(unsigned short);
    unsigned short* WTb = (unsigned short*)p; p += (size_t)D_OUT * D_IN * sizeof(unsigned short);
    float* f_src = (float*)p;  p += (size_t)n * sizeof(float);
    float* f_dst = (float*)p;  p += (size_t)n * sizeof(float);
    int*  gcnt   = (int*)p;    p += (size_t)(nb + 1) * sizeof(int);
    int2* ovf    = (int2*)p;   p += (size_t)OVFCAP * sizeof(int2);
    int*  gkeys  = (int*)p;    p += (size_t)nb * CAPG * sizeof(int);

    const int gemm_blocks = (n + BM - 1) / BM;
    const int nbf = (E + CH - 1) / CH;

    k_wt<<<D_OUT, 256, 0, stream>>>(W, WTb, gcnt, nb);
    k_fused<<<nbf + gemm_blocks, 256, 0, stream>>>(x, WTb, a, hb, f_src, f_dst, n,
                                                   src, dst, gcnt, ovf, gkeys, E, nb, nbf);
    k_bagg<<<nb, 512, 0, stream>>>(hb, f_src, f_dst, gcnt, ovf, gkeys, out, n, nb);
}